// Round 4
// baseline (137.903 us; speedup 1.0000x reference)
//
#include <hip/hip_runtime.h>
#include <hip/hip_bf16.h>

#define B_ 4
#define C_IN_ 384
#define C_OUT_ 768
#define N_ 8192
#define K_ 16
#define FANIN_ 192     // 2*C_IN/GROUPS
#define GPC 96         // original channels per group
#define NT 32          // n-columns per block
#define LDW (GPC + 1)  // LDS row stride in dwords (97: +1 pad -> <=2-way conflicts)

typedef float f32x4 __attribute__((ext_vector_type(4)));
typedef short bf16x8 __attribute__((ext_vector_type(8)));

__device__ __forceinline__ unsigned short f2b(float f) {
  union { float f; unsigned u; } v; v.f = f;
  unsigned r = v.u + 0x7FFFu + ((v.u >> 16) & 1u);  // RNE
  return (unsigned short)(r >> 16);
}
__device__ __forceinline__ float hi_f(unsigned u) {  // bf16 in high 16 bits -> f32
  union { unsigned u; float f; } v; v.u = u & 0xffff0000u; return v.f;
}
__device__ __forceinline__ float lo_f(unsigned u) {  // bf16 in low 16 bits -> f32
  union { unsigned u; float f; } v; v.u = u << 16; return v.f;
}

// ---- kernel 1: W fp32 -> bf16 ----
__global__ __launch_bounds__(256) void wconv_kernel(const float* __restrict__ W,
                                                    unsigned short* __restrict__ Wb) {
  int i = blockIdx.x * 256 + threadIdx.x;
  if (i < C_OUT_ * FANIN_) Wb[i] = f2b(W[i]);
}

// ---- kernel 2: transpose x [B][C][N] f32 -> xt [B][N][C] bf16 ----
__global__ __launch_bounds__(256) void transpose_kernel(const float* __restrict__ x,
                                                        unsigned short* __restrict__ xt) {
  __shared__ float tile[32][65];
  int n0 = blockIdx.x * 32;
  int c0 = blockIdx.y * 64;
  int b  = blockIdx.z;
  int tx = threadIdx.x & 31;   // n offset
  int ty = threadIdx.x >> 5;   // 0..7
  const float* xp = x + (size_t)b * C_IN_ * N_;
  #pragma unroll
  for (int r = 0; r < 8; ++r) {
    int c = c0 + r * 8 + ty;
    tile[tx][r * 8 + ty] = xp[(size_t)c * N_ + n0 + tx];   // coalesced along n
  }
  __syncthreads();
  unsigned short* outp = xt + ((size_t)b * N_ + n0) * C_IN_ + c0;
  int cp = threadIdx.x & 31;   // channel pair
  int ny = threadIdx.x >> 5;
  #pragma unroll
  for (int p = 0; p < 4; ++p) {
    int nl = ny + p * 8;
    unsigned pk = (unsigned)f2b(tile[nl][cp * 2]) |
                  ((unsigned)f2b(tile[nl][cp * 2 + 1]) << 16);
    *(unsigned*)(outp + (size_t)nl * C_IN_ + cp * 2) = pk;  // coalesced along c
  }
}

// ---- kernel 3: (b,g)-partitioned gather+max -> LDS -> group-g MFMA GEMM ----
// Block handles ONE (batch, group) pair and NT columns. The 16 (b,g) pairs are
// pinned to XCDs via blockIdx%8 round-robin: per-XCD gather working set =
// 2 pairs x 1.57 MB = 3.15 MB -> L2-resident (vs 25 MB before).
__global__ __launch_bounds__(512) void mrconv_kernel(
    const unsigned short* __restrict__ xt,   // [B][N][C_IN] bf16
    const int* __restrict__ eidx,            // [2][B][N][K]
    const unsigned short* __restrict__ Wb,   // [C_OUT][FANIN] bf16
    const float* __restrict__ bias,          // [C_OUT]
    float* __restrict__ out)                 // [B][C_OUT][N]
{
  __shared__ unsigned m_lds[NT][LDW];        // dword = x_c | rel_c<<16 (group-local)
  int ib   = blockIdx.x;
  int p    = (ib & 7) | (((ib >> 3) & 1) << 3);  // pair id 0..15, pair%8 == XCD
  int tile = ib >> 4;
  int b    = p & 3;
  int g    = p >> 2;
  int n0   = tile * NT;
  int tid  = threadIdx.x;
  int wv   = tid >> 6;
  int lane = tid & 63;
  int q    = lane >> 4;        // quarter-wave: column select / MFMA lhi
  int r15  = lane & 15;

  const unsigned short* xg = xt + (size_t)b * N_ * C_IN_ + g * GPC;  // group slab
  const int* e0p = eidx + ((size_t)b * N_) * K_;          // edge_index[0][b]
  const int* e1p = eidx + ((size_t)(B_ + b) * N_) * K_;   // edge_index[1][b]

  // -------- phase 1: gather + max-relative (quarter-wave per column) --------
  int nl = wv * 4 + q;                       // 8 waves x 4 cols = 32
  int n  = n0 + nl;
  int cb = r15 * 6;                          // local channel base (16 x 6 = 96)

  // preload indices: lane r15 <-> k; wave reads 64 consecutive ints (coalesced)
  int ind0 = e0p[(size_t)n * K_ + r15];
  int ind1 = e1p[(size_t)n * K_ + r15];
  uint3 xv = *(const uint3*)(xg + (size_t)n * C_IN_ + cb);   // self (6 ch)

  float rel[6];
  #pragma unroll
  for (int c = 0; c < 6; ++c) rel[c] = -1e30f;

  #pragma unroll 4
  for (int k = 0; k < K_; ++k) {
    int j = __shfl(ind0, (lane & 48) + k);   // broadcast within quarter
    int i = __shfl(ind1, (lane & 48) + k);
    uint3 vj = *(const uint3*)(xg + (size_t)j * C_IN_ + cb);
    uint3 vi = *(const uint3*)(xg + (size_t)i * C_IN_ + cb);
    unsigned uj[3] = {vj.x, vj.y, vj.z};
    unsigned ui[3] = {vi.x, vi.y, vi.z};
    #pragma unroll
    for (int d = 0; d < 3; ++d) {
      rel[2*d]   = fmaxf(rel[2*d],   lo_f(uj[d]) - lo_f(ui[d]));
      rel[2*d+1] = fmaxf(rel[2*d+1], hi_f(uj[d]) - hi_f(ui[d]));
    }
  }

  // pack interleaved (x_c, rel_c): dword c = x_c | rel_c<<16
  unsigned xd[3] = {xv.x, xv.y, xv.z};
  unsigned od[6];
  #pragma unroll
  for (int c = 0; c < 6; ++c) {
    union { float f; unsigned u; } r; r.f = rel[c];
    unsigned rh = (r.u + 0x7fffu + ((r.u >> 16) & 1u)) & 0xffff0000u;  // RNE, high
    unsigned xs = (c & 1) ? (xd[c >> 1] >> 16) : (xd[c >> 1] & 0xffffu);
    od[c] = xs | rh;
  }
  unsigned* dst = &m_lds[nl][cb];
  *(uint2*)(dst)     = (uint2){od[0], od[1]};
  *(uint2*)(dst + 2) = (uint2){od[2], od[3]};
  *(uint2*)(dst + 4) = (uint2){od[4], od[5]};
  __syncthreads();

  // -------- phase 2: group-g GEMM via MFMA --------
  // wave: rows slab (wv>>1)*48 (3x16), cols (wv&1)*16 of the NT=32 tile
  int rsl = (wv >> 1) * 48;                  // local cout base (0/48/96/144)
  int ct  = wv & 1;
  const unsigned short* Wg = Wb + (size_t)(g * 192 + rsl) * FANIN_;

  f32x4 acc[3];
  #pragma unroll
  for (int rt = 0; rt < 3; ++rt) acc[rt] = (f32x4){0.f, 0.f, 0.f, 0.f};

  #pragma unroll
  for (int ks = 0; ks < 6; ++ks) {           // K = 192 = 6 x 32
    int k0 = ks * 32 + q * 8;                // shorts; dword ks*16 + q*4 (16B aligned)
    bf16x8 bfrag = *(const bf16x8*)((const unsigned short*)&m_lds[ct * 16 + r15][0] + k0);
    #pragma unroll
    for (int rt = 0; rt < 3; ++rt) {
      bf16x8 afrag = *(const bf16x8*)(Wg + (size_t)(rt * 16 + r15) * FANIN_ + k0);
      acc[rt] = __builtin_amdgcn_mfma_f32_16x16x32_bf16(afrag, bfrag, acc[rt], 0, 0, 0);
    }
  }

  // -------- epilogue: bias + ReLU, non-temporal store --------
  float* outb = out + ((size_t)b * C_OUT_ + g * 192 + rsl) * N_;
  int n_out = n0 + ct * 16 + r15;            // D col = lane&15
  #pragma unroll
  for (int rt = 0; rt < 3; ++rt) {
    #pragma unroll
    for (int r = 0; r < 4; ++r) {
      int co = rt * 16 + q * 4 + r;          // D row = (lane>>4)*4 + reg
      float v = acc[rt][r] + bias[g * 192 + rsl + co];
      v = v > 0.f ? v : 0.f;
      __builtin_nontemporal_store(v, &outb[(size_t)co * N_ + n_out]);
    }
  }
}

extern "C" void kernel_launch(void* const* d_in, const int* in_sizes, int n_in,
                              void* d_out, int out_size, void* d_ws, size_t ws_size,
                              hipStream_t stream) {
  const float* x    = (const float*)d_in[0];
  const int*   eidx = (const int*)d_in[1];
  const float* W    = (const float*)d_in[2];
  const float* bias = (const float*)d_in[3];
  float* out = (float*)d_out;

  unsigned short* xt = (unsigned short*)d_ws;                 // B*N*C_IN bf16 = 25.2 MB
  unsigned short* Wb = xt + (size_t)B_ * N_ * C_IN_;          // C_OUT*FANIN bf16 = 0.3 MB

  wconv_kernel<<<(C_OUT_ * FANIN_ + 255) / 256, 256, 0, stream>>>(W, Wb);

  dim3 tg(N_ / 32, C_IN_ / 64, B_);
  transpose_kernel<<<tg, 256, 0, stream>>>(x, xt);

  int nblk = 16 * (N_ / NT);   // (b,g) pairs x tiles = 4096
  mrconv_kernel<<<nblk, 512, 0, stream>>>(xt, eidx, Wb, bias, out);
}